// Round 7
// baseline (3595.358 us; speedup 1.0000x reference)
//
#include <hip/hip_runtime.h>

#define NN 50000
#define EE 800000
#define DD 256
#define DFFC 512
#define EPSF 1e-5f

// ---------------------------------------------------------------------------
// K1: scatter-aggregate  agg[dst] += x[src]   (one wave per edge, float4/lane)
// ---------------------------------------------------------------------------
__global__ __launch_bounds__(256) void k_scatter(const float* __restrict__ x,
                                                 const int* __restrict__ ei,
                                                 float* __restrict__ agg) {
    int t = blockIdx.x * 256 + threadIdx.x;   // < EE*64 = 51.2M, fits int
    int e = t >> 6;
    int lane = t & 63;
    if (e >= EE) return;
    int s = ei[e];
    int d = ei[EE + e];
    float4 v = *reinterpret_cast<const float4*>(x + s * DD + lane * 4);
    float* o = agg + d * DD + lane * 4;
    unsafeAtomicAdd(o + 0, v.x);
    unsafeAtomicAdd(o + 1, v.y);
    unsafeAtomicAdd(o + 2, v.z);
    unsafeAtomicAdd(o + 3, v.w);
}

// ---------------------------------------------------------------------------
// K2: h = LayerNorm(x + agg@Wn + x@Wr + b_gnn)      BM=32 rows, 256 cols/block
// thread: rows r0..r0+7 (wave-uniform), cols c..c+3 (lane-distinct)
// ---------------------------------------------------------------------------
__global__ __launch_bounds__(256, 2) void k_gnn_ln(
    const float* __restrict__ x, const float* __restrict__ agg,
    const float* __restrict__ Wn, const float* __restrict__ Wr,
    const float* __restrict__ bg, const float* __restrict__ g1,
    const float* __restrict__ be1, float* __restrict__ h) {
    __shared__ float swn[32][256];   // W_nbr K-chunk
    __shared__ float swr[32][256];   // W_root K-chunk
    __shared__ float sta[32][36];    // agg tile, transposed [k][row], pad 4
    __shared__ float stx[32][36];    // x   tile, transposed

    const int tid = threadIdx.x;
    const int lane = tid & 63;
    const int w = tid >> 6;
    const int c = lane * 4;
    const int r0 = w * 8;
    const int row0 = blockIdx.x * 32;

    float acc[8][4];
#pragma unroll
    for (int r = 0; r < 8; ++r)
#pragma unroll
        for (int j = 0; j < 4; ++j) acc[r][j] = 0.f;

    const int lr = tid >> 3;        // staging row 0..31
    const int lk = (tid & 7) * 4;   // staging k   0..28
    int lrow = row0 + lr;
    if (lrow >= NN) lrow = NN - 1;

    for (int k0 = 0; k0 < DD; k0 += 32) {
        __syncthreads();
#pragma unroll
        for (int i = 0; i < 8; ++i) {
            int flat = i * 1024 + tid * 4;
            int kk = flat >> 8, cc = flat & 255;
            *reinterpret_cast<float4*>(&swn[kk][cc]) =
                *reinterpret_cast<const float4*>(Wn + (k0 + kk) * DD + cc);
            *reinterpret_cast<float4*>(&swr[kk][cc]) =
                *reinterpret_cast<const float4*>(Wr + (k0 + kk) * DD + cc);
        }
        float4 va = *reinterpret_cast<const float4*>(agg + lrow * DD + k0 + lk);
        float4 vx = *reinterpret_cast<const float4*>(x + lrow * DD + k0 + lk);
        sta[lk + 0][lr] = va.x; sta[lk + 1][lr] = va.y;
        sta[lk + 2][lr] = va.z; sta[lk + 3][lr] = va.w;
        stx[lk + 0][lr] = vx.x; stx[lk + 1][lr] = vx.y;
        stx[lk + 2][lr] = vx.z; stx[lk + 3][lr] = vx.w;
        __syncthreads();
#pragma unroll 4
        for (int kk = 0; kk < 32; ++kk) {
            float4 wn4 = *reinterpret_cast<const float4*>(&swn[kk][c]);
            float4 wr4 = *reinterpret_cast<const float4*>(&swr[kk][c]);
            float4 a0 = *reinterpret_cast<const float4*>(&sta[kk][r0]);
            float4 a1 = *reinterpret_cast<const float4*>(&sta[kk][r0 + 4]);
            float4 b0 = *reinterpret_cast<const float4*>(&stx[kk][r0]);
            float4 b1 = *reinterpret_cast<const float4*>(&stx[kk][r0 + 4]);
            float aa[8] = {a0.x, a0.y, a0.z, a0.w, a1.x, a1.y, a1.z, a1.w};
            float xx[8] = {b0.x, b0.y, b0.z, b0.w, b1.x, b1.y, b1.z, b1.w};
#pragma unroll
            for (int r = 0; r < 8; ++r) {
                acc[r][0] += aa[r] * wn4.x + xx[r] * wr4.x;
                acc[r][1] += aa[r] * wn4.y + xx[r] * wr4.y;
                acc[r][2] += aa[r] * wn4.z + xx[r] * wr4.z;
                acc[r][3] += aa[r] * wn4.w + xx[r] * wr4.w;
            }
        }
    }

    // epilogue: + b_gnn + x residual, LayerNorm, store h
    float4 bgv = *reinterpret_cast<const float4*>(bg + c);
    float4 g1v = *reinterpret_cast<const float4*>(g1 + c);
    float4 b1v = *reinterpret_cast<const float4*>(be1 + c);
#pragma unroll
    for (int r = 0; r < 8; ++r) {
        int row = row0 + r0 + r;
        bool valid = row < NN;
        int rr = valid ? row : NN - 1;
        float4 xr = *reinterpret_cast<const float4*>(x + rr * DD + c);
        float v0 = acc[r][0] + bgv.x + xr.x;
        float v1 = acc[r][1] + bgv.y + xr.y;
        float v2 = acc[r][2] + bgv.z + xr.z;
        float v3 = acc[r][3] + bgv.w + xr.w;
        float s = v0 + v1 + v2 + v3;
        float q = v0 * v0 + v1 * v1 + v2 * v2 + v3 * v3;
#pragma unroll
        for (int off = 32; off >= 1; off >>= 1) {
            s += __shfl_xor(s, off, 64);
            q += __shfl_xor(q, off, 64);
        }
        float mu = s * (1.f / 256.f);
        float var = q * (1.f / 256.f) - mu * mu;
        float rs = rsqrtf(var + EPSF);
        float4 o;
        o.x = (v0 - mu) * rs * g1v.x + b1v.x;
        o.y = (v1 - mu) * rs * g1v.y + b1v.y;
        o.z = (v2 - mu) * rs * g1v.z + b1v.z;
        o.w = (v3 - mu) * rs * g1v.w + b1v.w;
        if (valid) *reinterpret_cast<float4*>(h + row * DD + c) = o;
    }
}

// ---------------------------------------------------------------------------
// K3: out = LayerNorm(h + relu(h@W1+b1)@W2 + b2), fused; DFF split in 2 halves
// h lives in d_out and is overwritten in place (each block only touches its rows)
// ---------------------------------------------------------------------------
__global__ __launch_bounds__(256, 2) void k_ffn_ln(
    float* __restrict__ hout, const float* __restrict__ W1,
    const float* __restrict__ b1, const float* __restrict__ W2,
    const float* __restrict__ b2, const float* __restrict__ g2,
    const float* __restrict__ be2) {
    __shared__ float sw[32][256];    // staged W1/W2 K-chunk
    __shared__ float sht[32][36];    // transposed h chunk
    __shared__ float st[32][264];    // relu(h@W1half+b1) tile, row-major pad 8

    const int tid = threadIdx.x;
    const int lane = tid & 63;
    const int w = tid >> 6;
    const int c = lane * 4;
    const int r0 = w * 8;
    const int row0 = blockIdx.x * 32;
    const int lr = tid >> 3;
    const int lk = (tid & 7) * 4;
    int lrow = row0 + lr;
    if (lrow >= NN) lrow = NN - 1;

    float acc2[8][4];
#pragma unroll
    for (int r = 0; r < 8; ++r)
#pragma unroll
        for (int j = 0; j < 4; ++j) acc2[r][j] = 0.f;

    for (int half = 0; half < 2; ++half) {
        float acc1[8][4];
#pragma unroll
        for (int r = 0; r < 8; ++r)
#pragma unroll
            for (int j = 0; j < 4; ++j) acc1[r][j] = 0.f;

        // ---- GEMM1: acc1 = h_rows @ W1[:, half*256 + c] ----
        for (int k0 = 0; k0 < DD; k0 += 32) {
            __syncthreads();
#pragma unroll
            for (int i = 0; i < 8; ++i) {
                int flat = i * 1024 + tid * 4;
                int kk = flat >> 8, cc = flat & 255;
                *reinterpret_cast<float4*>(&sw[kk][cc]) =
                    *reinterpret_cast<const float4*>(W1 + (k0 + kk) * DFFC + half * 256 + cc);
            }
            float4 vh = *reinterpret_cast<const float4*>(hout + lrow * DD + k0 + lk);
            sht[lk + 0][lr] = vh.x; sht[lk + 1][lr] = vh.y;
            sht[lk + 2][lr] = vh.z; sht[lk + 3][lr] = vh.w;
            __syncthreads();
#pragma unroll 4
            for (int kk = 0; kk < 32; ++kk) {
                float4 w4 = *reinterpret_cast<const float4*>(&sw[kk][c]);
                float4 a0 = *reinterpret_cast<const float4*>(&sht[kk][r0]);
                float4 a1 = *reinterpret_cast<const float4*>(&sht[kk][r0 + 4]);
                float aa[8] = {a0.x, a0.y, a0.z, a0.w, a1.x, a1.y, a1.z, a1.w};
#pragma unroll
                for (int r = 0; r < 8; ++r) {
                    acc1[r][0] += aa[r] * w4.x;
                    acc1[r][1] += aa[r] * w4.y;
                    acc1[r][2] += aa[r] * w4.z;
                    acc1[r][3] += aa[r] * w4.w;
                }
            }
        }
        __syncthreads();
        // ---- bias + relu, stash t in LDS ----
        {
            float4 bv = *reinterpret_cast<const float4*>(b1 + half * 256 + c);
#pragma unroll
            for (int r = 0; r < 8; ++r) {
                float4 tv;
                tv.x = fmaxf(acc1[r][0] + bv.x, 0.f);
                tv.y = fmaxf(acc1[r][1] + bv.y, 0.f);
                tv.z = fmaxf(acc1[r][2] + bv.z, 0.f);
                tv.w = fmaxf(acc1[r][3] + bv.w, 0.f);
                *reinterpret_cast<float4*>(&st[r0 + r][c]) = tv;
            }
        }
        // ---- GEMM2: acc2 += t @ W2[half*256 + k, :] ----
        for (int k0 = 0; k0 < 256; k0 += 32) {
            __syncthreads();
#pragma unroll
            for (int i = 0; i < 8; ++i) {
                int flat = i * 1024 + tid * 4;
                int kk = flat >> 8, cc = flat & 255;
                *reinterpret_cast<float4*>(&sw[kk][cc]) =
                    *reinterpret_cast<const float4*>(W2 + (half * 256 + k0 + kk) * DD + cc);
            }
            __syncthreads();
#pragma unroll 2
            for (int kk4 = 0; kk4 < 32; kk4 += 4) {
                float4 w40 = *reinterpret_cast<const float4*>(&sw[kk4 + 0][c]);
                float4 w41 = *reinterpret_cast<const float4*>(&sw[kk4 + 1][c]);
                float4 w42 = *reinterpret_cast<const float4*>(&sw[kk4 + 2][c]);
                float4 w43 = *reinterpret_cast<const float4*>(&sw[kk4 + 3][c]);
#pragma unroll
                for (int r = 0; r < 8; ++r) {
                    // FIXED (R1): was &st[r0+r][kk4] (k0 cancelled) — GEMM2 re-read
                    // t[0:32] for every k0 block. Must read t at local col k0+kk4.
                    float4 t4 = *reinterpret_cast<const float4*>(&st[r0 + r][k0 + kk4]);
                    acc2[r][0] += t4.x * w40.x + t4.y * w41.x + t4.z * w42.x + t4.w * w43.x;
                    acc2[r][1] += t4.x * w40.y + t4.y * w41.y + t4.z * w42.y + t4.w * w43.y;
                    acc2[r][2] += t4.x * w40.z + t4.y * w41.z + t4.z * w42.z + t4.w * w43.z;
                    acc2[r][3] += t4.x * w40.w + t4.y * w41.w + t4.z * w42.w + t4.w * w43.w;
                }
            }
        }
        __syncthreads();   // st will be overwritten next half
    }

    // ---- epilogue: + b2 + h residual, LayerNorm, store out (in place) ----
    float4 b2v = *reinterpret_cast<const float4*>(b2 + c);
    float4 g2v = *reinterpret_cast<const float4*>(g2 + c);
    float4 e2v = *reinterpret_cast<const float4*>(be2 + c);
#pragma unroll
    for (int r = 0; r < 8; ++r) {
        int row = row0 + r0 + r;
        bool valid = row < NN;
        int rr = valid ? row : NN - 1;
        float4 hr = *reinterpret_cast<const float4*>(hout + rr * DD + c);
        float v0 = acc2[r][0] + b2v.x + hr.x;
        float v1 = acc2[r][1] + b2v.y + hr.y;
        float v2 = acc2[r][2] + b2v.z + hr.z;
        float v3 = acc2[r][3] + b2v.w + hr.w;
        float s = v0 + v1 + v2 + v3;
        float q = v0 * v0 + v1 * v1 + v2 * v2 + v3 * v3;
#pragma unroll
        for (int off = 32; off >= 1; off >>= 1) {
            s += __shfl_xor(s, off, 64);
            q += __shfl_xor(q, off, 64);
        }
        float mu = s * (1.f / 256.f);
        float var = q * (1.f / 256.f) - mu * mu;
        float rs = rsqrtf(var + EPSF);
        float4 o;
        o.x = (v0 - mu) * rs * g2v.x + e2v.x;
        o.y = (v1 - mu) * rs * g2v.y + e2v.y;
        o.z = (v2 - mu) * rs * g2v.z + e2v.z;
        o.w = (v3 - mu) * rs * g2v.w + e2v.w;
        if (valid) *reinterpret_cast<float4*>(hout + row * DD + c) = o;
    }
}

// ---------------------------------------------------------------------------
extern "C" void kernel_launch(void* const* d_in, const int* in_sizes, int n_in,
                              void* d_out, int out_size, void* d_ws, size_t ws_size,
                              hipStream_t stream) {
    const float* x   = (const float*)d_in[0];
    const int*   ei  = (const int*)d_in[1];   // edge_index as int32
    const float* Wn  = (const float*)d_in[2];
    const float* Wr  = (const float*)d_in[3];
    const float* bg  = (const float*)d_in[4];
    const float* W1  = (const float*)d_in[5];
    const float* b1  = (const float*)d_in[6];
    const float* W2  = (const float*)d_in[7];
    const float* b2  = (const float*)d_in[8];
    const float* g1  = (const float*)d_in[9];
    const float* be1 = (const float*)d_in[10];
    const float* g2  = (const float*)d_in[11];
    const float* be2 = (const float*)d_in[12];
    float* out = (float*)d_out;
    float* agg = (float*)d_ws;                // N*D fp32 = 51.2 MB scratch

    hipMemsetAsync(agg, 0, (size_t)NN * DD * sizeof(float), stream);
    k_scatter<<<EE / 4, 256, 0, stream>>>(x, ei, agg);
    int nblk = (NN + 31) / 32;                // 1563
    k_gnn_ln<<<nblk, 256, 0, stream>>>(x, agg, Wn, Wr, bg, g1, be1, out);
    k_ffn_ln<<<nblk, 256, 0, stream>>>(out, W1, b1, W2, b2, g2, be2);
}

// Round 10
// 1023.616 us; speedup vs baseline: 3.5124x; 3.5124x over previous
//
#include <hip/hip_runtime.h>

#define NN 50000
#define EE 800000
#define DD 256
#define DFFC 512
#define EPSF 1e-5f
#define CAP 64   // per-node edge bucket capacity; Poisson(16) => P(deg>64) ~ 1e-12

// ---------------------------------------------------------------------------
// K1a: bucket-fill.  pos = cnt[d]++; slot[d*CAP+pos] = s.  800K int atomics.
// Overflow (essentially impossible) falls back to direct atomics into agg
// (agg is zeroed before this kernel runs).
// ---------------------------------------------------------------------------
__global__ __launch_bounds__(256) void k_fill(const float* __restrict__ x,
                                              const int* __restrict__ ei,
                                              int* __restrict__ cnt,
                                              int* __restrict__ slot,
                                              float* __restrict__ agg) {
    int e = blockIdx.x * 256 + threadIdx.x;
    if (e >= EE) return;
    int s = ei[e];
    int d = ei[EE + e];
    int pos = atomicAdd(&cnt[d], 1);
    if (pos < CAP) {
        slot[d * CAP + pos] = s;
    } else {
        const float* xr = x + (size_t)s * DD;
        float* ar = agg + (size_t)d * DD;
        for (int j = 0; j < DD; ++j) unsafeAtomicAdd(ar + j, xr[j]);
    }
}

// ---------------------------------------------------------------------------
// K1b: gather-reduce.  One wave per dst node; lane owns cols c..c+3.
// slot reads are wave-uniform (LDS-free broadcast); x row reads coalesced 1KB.
// ---------------------------------------------------------------------------
__global__ __launch_bounds__(256) void k_gather(const float* __restrict__ x,
                                                const int* __restrict__ cnt,
                                                const int* __restrict__ slot,
                                                float* __restrict__ agg) {
    int n = blockIdx.x * 4 + (threadIdx.x >> 6);
    int lane = threadIdx.x & 63;
    if (n >= NN) return;
    int deg = cnt[n];
    int m = deg < CAP ? deg : CAP;
    int c = lane * 4;
    float4 sum = {0.f, 0.f, 0.f, 0.f};
    const int* sl = slot + n * CAP;
#pragma unroll 2
    for (int i = 0; i < m; ++i) {
        int s = sl[i];
        float4 v = *reinterpret_cast<const float4*>(x + (size_t)s * DD + c);
        sum.x += v.x; sum.y += v.y; sum.z += v.z; sum.w += v.w;
    }
    float* out = agg + (size_t)n * DD + c;
    if (deg > CAP) {   // rare: overflow edges were atomically added in k_fill
        float4 b = *reinterpret_cast<const float4*>(out);
        sum.x += b.x; sum.y += b.y; sum.z += b.z; sum.w += b.w;
    }
    *reinterpret_cast<float4*>(out) = sum;
}

// ---------------------------------------------------------------------------
// K1 (fallback if ws too small): atomic scatter  agg[dst] += x[src]
// ---------------------------------------------------------------------------
__global__ __launch_bounds__(256) void k_scatter(const float* __restrict__ x,
                                                 const int* __restrict__ ei,
                                                 float* __restrict__ agg) {
    int t = blockIdx.x * 256 + threadIdx.x;
    int e = t >> 6;
    int lane = t & 63;
    if (e >= EE) return;
    int s = ei[e];
    int d = ei[EE + e];
    float4 v = *reinterpret_cast<const float4*>(x + s * DD + lane * 4);
    float* o = agg + d * DD + lane * 4;
    unsafeAtomicAdd(o + 0, v.x);
    unsafeAtomicAdd(o + 1, v.y);
    unsafeAtomicAdd(o + 2, v.z);
    unsafeAtomicAdd(o + 3, v.w);
}

// ---------------------------------------------------------------------------
// K2: h = LayerNorm(x + agg@Wn + x@Wr + b_gnn)      BM=32 rows, 256 cols/block
// ---------------------------------------------------------------------------
__global__ __launch_bounds__(256, 2) void k_gnn_ln(
    const float* __restrict__ x, const float* __restrict__ agg,
    const float* __restrict__ Wn, const float* __restrict__ Wr,
    const float* __restrict__ bg, const float* __restrict__ g1,
    const float* __restrict__ be1, float* __restrict__ h) {
    __shared__ float swn[32][256];   // W_nbr K-chunk
    __shared__ float swr[32][256];   // W_root K-chunk
    __shared__ float sta[32][36];    // agg tile, transposed [k][row], pad 4
    __shared__ float stx[32][36];    // x   tile, transposed

    const int tid = threadIdx.x;
    const int lane = tid & 63;
    const int w = tid >> 6;
    const int c = lane * 4;
    const int r0 = w * 8;
    const int row0 = blockIdx.x * 32;

    float acc[8][4];
#pragma unroll
    for (int r = 0; r < 8; ++r)
#pragma unroll
        for (int j = 0; j < 4; ++j) acc[r][j] = 0.f;

    const int lr = tid >> 3;        // staging row 0..31
    const int lk = (tid & 7) * 4;   // staging k   0..28
    int lrow = row0 + lr;
    if (lrow >= NN) lrow = NN - 1;

    for (int k0 = 0; k0 < DD; k0 += 32) {
        __syncthreads();
#pragma unroll
        for (int i = 0; i < 8; ++i) {
            int flat = i * 1024 + tid * 4;
            int kk = flat >> 8, cc = flat & 255;
            *reinterpret_cast<float4*>(&swn[kk][cc]) =
                *reinterpret_cast<const float4*>(Wn + (k0 + kk) * DD + cc);
            *reinterpret_cast<float4*>(&swr[kk][cc]) =
                *reinterpret_cast<const float4*>(Wr + (k0 + kk) * DD + cc);
        }
        float4 va = *reinterpret_cast<const float4*>(agg + lrow * DD + k0 + lk);
        float4 vx = *reinterpret_cast<const float4*>(x + lrow * DD + k0 + lk);
        sta[lk + 0][lr] = va.x; sta[lk + 1][lr] = va.y;
        sta[lk + 2][lr] = va.z; sta[lk + 3][lr] = va.w;
        stx[lk + 0][lr] = vx.x; stx[lk + 1][lr] = vx.y;
        stx[lk + 2][lr] = vx.z; stx[lk + 3][lr] = vx.w;
        __syncthreads();
#pragma unroll 4
        for (int kk = 0; kk < 32; ++kk) {
            float4 wn4 = *reinterpret_cast<const float4*>(&swn[kk][c]);
            float4 wr4 = *reinterpret_cast<const float4*>(&swr[kk][c]);
            float4 a0 = *reinterpret_cast<const float4*>(&sta[kk][r0]);
            float4 a1 = *reinterpret_cast<const float4*>(&sta[kk][r0 + 4]);
            float4 b0 = *reinterpret_cast<const float4*>(&stx[kk][r0]);
            float4 b1 = *reinterpret_cast<const float4*>(&stx[kk][r0 + 4]);
            float aa[8] = {a0.x, a0.y, a0.z, a0.w, a1.x, a1.y, a1.z, a1.w};
            float xx[8] = {b0.x, b0.y, b0.z, b0.w, b1.x, b1.y, b1.z, b1.w};
#pragma unroll
            for (int r = 0; r < 8; ++r) {
                acc[r][0] += aa[r] * wn4.x + xx[r] * wr4.x;
                acc[r][1] += aa[r] * wn4.y + xx[r] * wr4.y;
                acc[r][2] += aa[r] * wn4.z + xx[r] * wr4.z;
                acc[r][3] += aa[r] * wn4.w + xx[r] * wr4.w;
            }
        }
    }

    float4 bgv = *reinterpret_cast<const float4*>(bg + c);
    float4 g1v = *reinterpret_cast<const float4*>(g1 + c);
    float4 b1v = *reinterpret_cast<const float4*>(be1 + c);
#pragma unroll
    for (int r = 0; r < 8; ++r) {
        int row = row0 + r0 + r;
        bool valid = row < NN;
        int rr = valid ? row : NN - 1;
        float4 xr = *reinterpret_cast<const float4*>(x + rr * DD + c);
        float v0 = acc[r][0] + bgv.x + xr.x;
        float v1 = acc[r][1] + bgv.y + xr.y;
        float v2 = acc[r][2] + bgv.z + xr.z;
        float v3 = acc[r][3] + bgv.w + xr.w;
        float s = v0 + v1 + v2 + v3;
        float q = v0 * v0 + v1 * v1 + v2 * v2 + v3 * v3;
#pragma unroll
        for (int off = 32; off >= 1; off >>= 1) {
            s += __shfl_xor(s, off, 64);
            q += __shfl_xor(q, off, 64);
        }
        float mu = s * (1.f / 256.f);
        float var = q * (1.f / 256.f) - mu * mu;
        float rs = rsqrtf(var + EPSF);
        float4 o;
        o.x = (v0 - mu) * rs * g1v.x + b1v.x;
        o.y = (v1 - mu) * rs * g1v.y + b1v.y;
        o.z = (v2 - mu) * rs * g1v.z + b1v.z;
        o.w = (v3 - mu) * rs * g1v.w + b1v.w;
        if (valid) *reinterpret_cast<float4*>(h + row * DD + c) = o;
    }
}

// ---------------------------------------------------------------------------
// K3: out = LayerNorm(h + relu(h@W1+b1)@W2 + b2), fused; DFF split in 2 halves
// ---------------------------------------------------------------------------
__global__ __launch_bounds__(256, 2) void k_ffn_ln(
    float* __restrict__ hout, const float* __restrict__ W1,
    const float* __restrict__ b1, const float* __restrict__ W2,
    const float* __restrict__ b2, const float* __restrict__ g2,
    const float* __restrict__ be2) {
    __shared__ float sw[32][256];    // staged W1/W2 K-chunk
    __shared__ float sht[32][36];    // transposed h chunk
    __shared__ float st[32][264];    // relu(h@W1half+b1) tile, row-major pad 8

    const int tid = threadIdx.x;
    const int lane = tid & 63;
    const int w = tid >> 6;
    const int c = lane * 4;
    const int r0 = w * 8;
    const int row0 = blockIdx.x * 32;
    const int lr = tid >> 3;
    const int lk = (tid & 7) * 4;
    int lrow = row0 + lr;
    if (lrow >= NN) lrow = NN - 1;

    float acc2[8][4];
#pragma unroll
    for (int r = 0; r < 8; ++r)
#pragma unroll
        for (int j = 0; j < 4; ++j) acc2[r][j] = 0.f;

    for (int half = 0; half < 2; ++half) {
        float acc1[8][4];
#pragma unroll
        for (int r = 0; r < 8; ++r)
#pragma unroll
            for (int j = 0; j < 4; ++j) acc1[r][j] = 0.f;

        for (int k0 = 0; k0 < DD; k0 += 32) {
            __syncthreads();
#pragma unroll
            for (int i = 0; i < 8; ++i) {
                int flat = i * 1024 + tid * 4;
                int kk = flat >> 8, cc = flat & 255;
                *reinterpret_cast<float4*>(&sw[kk][cc]) =
                    *reinterpret_cast<const float4*>(W1 + (k0 + kk) * DFFC + half * 256 + cc);
            }
            float4 vh = *reinterpret_cast<const float4*>(hout + lrow * DD + k0 + lk);
            sht[lk + 0][lr] = vh.x; sht[lk + 1][lr] = vh.y;
            sht[lk + 2][lr] = vh.z; sht[lk + 3][lr] = vh.w;
            __syncthreads();
#pragma unroll 4
            for (int kk = 0; kk < 32; ++kk) {
                float4 w4 = *reinterpret_cast<const float4*>(&sw[kk][c]);
                float4 a0 = *reinterpret_cast<const float4*>(&sht[kk][r0]);
                float4 a1 = *reinterpret_cast<const float4*>(&sht[kk][r0 + 4]);
                float aa[8] = {a0.x, a0.y, a0.z, a0.w, a1.x, a1.y, a1.z, a1.w};
#pragma unroll
                for (int r = 0; r < 8; ++r) {
                    acc1[r][0] += aa[r] * w4.x;
                    acc1[r][1] += aa[r] * w4.y;
                    acc1[r][2] += aa[r] * w4.z;
                    acc1[r][3] += aa[r] * w4.w;
                }
            }
        }
        __syncthreads();
        {
            float4 bv = *reinterpret_cast<const float4*>(b1 + half * 256 + c);
#pragma unroll
            for (int r = 0; r < 8; ++r) {
                float4 tv;
                tv.x = fmaxf(acc1[r][0] + bv.x, 0.f);
                tv.y = fmaxf(acc1[r][1] + bv.y, 0.f);
                tv.z = fmaxf(acc1[r][2] + bv.z, 0.f);
                tv.w = fmaxf(acc1[r][3] + bv.w, 0.f);
                *reinterpret_cast<float4*>(&st[r0 + r][c]) = tv;
            }
        }
        for (int k0 = 0; k0 < 256; k0 += 32) {
            __syncthreads();
#pragma unroll
            for (int i = 0; i < 8; ++i) {
                int flat = i * 1024 + tid * 4;
                int kk = flat >> 8, cc = flat & 255;
                *reinterpret_cast<float4*>(&sw[kk][cc]) =
                    *reinterpret_cast<const float4*>(W2 + (half * 256 + k0 + kk) * DD + cc);
            }
            __syncthreads();
#pragma unroll 2
            for (int kk4 = 0; kk4 < 32; kk4 += 4) {
                float4 w40 = *reinterpret_cast<const float4*>(&sw[kk4 + 0][c]);
                float4 w41 = *reinterpret_cast<const float4*>(&sw[kk4 + 1][c]);
                float4 w42 = *reinterpret_cast<const float4*>(&sw[kk4 + 2][c]);
                float4 w43 = *reinterpret_cast<const float4*>(&sw[kk4 + 3][c]);
#pragma unroll
                for (int r = 0; r < 8; ++r) {
                    float4 t4 = *reinterpret_cast<const float4*>(&st[r0 + r][k0 + kk4]);
                    acc2[r][0] += t4.x * w40.x + t4.y * w41.x + t4.z * w42.x + t4.w * w43.x;
                    acc2[r][1] += t4.x * w40.y + t4.y * w41.y + t4.z * w42.y + t4.w * w43.y;
                    acc2[r][2] += t4.x * w40.z + t4.y * w41.z + t4.z * w42.z + t4.w * w43.z;
                    acc2[r][3] += t4.x * w40.w + t4.y * w41.w + t4.z * w42.w + t4.w * w43.w;
                }
            }
        }
        __syncthreads();
    }

    float4 b2v = *reinterpret_cast<const float4*>(b2 + c);
    float4 g2v = *reinterpret_cast<const float4*>(g2 + c);
    float4 e2v = *reinterpret_cast<const float4*>(be2 + c);
#pragma unroll
    for (int r = 0; r < 8; ++r) {
        int row = row0 + r0 + r;
        bool valid = row < NN;
        int rr = valid ? row : NN - 1;
        float4 hr = *reinterpret_cast<const float4*>(hout + rr * DD + c);
        float v0 = acc2[r][0] + b2v.x + hr.x;
        float v1 = acc2[r][1] + b2v.y + hr.y;
        float v2 = acc2[r][2] + b2v.z + hr.z;
        float v3 = acc2[r][3] + b2v.w + hr.w;
        float s = v0 + v1 + v2 + v3;
        float q = v0 * v0 + v1 * v1 + v2 * v2 + v3 * v3;
#pragma unroll
        for (int off = 32; off >= 1; off >>= 1) {
            s += __shfl_xor(s, off, 64);
            q += __shfl_xor(q, off, 64);
        }
        float mu = s * (1.f / 256.f);
        float var = q * (1.f / 256.f) - mu * mu;
        float rs = rsqrtf(var + EPSF);
        float4 o;
        o.x = (v0 - mu) * rs * g2v.x + e2v.x;
        o.y = (v1 - mu) * rs * g2v.y + e2v.y;
        o.z = (v2 - mu) * rs * g2v.z + e2v.z;
        o.w = (v3 - mu) * rs * g2v.w + e2v.w;
        if (valid) *reinterpret_cast<float4*>(hout + row * DD + c) = o;
    }
}

// ---------------------------------------------------------------------------
extern "C" void kernel_launch(void* const* d_in, const int* in_sizes, int n_in,
                              void* d_out, int out_size, void* d_ws, size_t ws_size,
                              hipStream_t stream) {
    const float* x   = (const float*)d_in[0];
    const int*   ei  = (const int*)d_in[1];
    const float* Wn  = (const float*)d_in[2];
    const float* Wr  = (const float*)d_in[3];
    const float* bg  = (const float*)d_in[4];
    const float* W1  = (const float*)d_in[5];
    const float* b1  = (const float*)d_in[6];
    const float* W2  = (const float*)d_in[7];
    const float* b2  = (const float*)d_in[8];
    const float* g1  = (const float*)d_in[9];
    const float* be1 = (const float*)d_in[10];
    const float* g2  = (const float*)d_in[11];
    const float* be2 = (const float*)d_in[12];
    float* out = (float*)d_out;
    float* agg = (float*)d_ws;

    const size_t aggBytes  = (size_t)NN * DD * sizeof(float);   // 51.2 MB
    const size_t cntBytes  = (size_t)NN * sizeof(int);          // 0.2 MB
    const size_t slotBytes = (size_t)NN * CAP * sizeof(int);    // 12.8 MB

    hipMemsetAsync(agg, 0, aggBytes, stream);
    if (ws_size >= aggBytes + cntBytes + slotBytes) {
        // CSR-bucket path: 800K int atomics + pure-read gather (no float atomics)
        int* cnt  = (int*)((char*)d_ws + aggBytes);
        int* slot = cnt + NN;
        hipMemsetAsync(cnt, 0, cntBytes, stream);
        k_fill<<<(EE + 255) / 256, 256, 0, stream>>>(x, ei, cnt, slot, agg);
        k_gather<<<(NN + 3) / 4, 256, 0, stream>>>(x, cnt, slot, agg);
    } else {
        // fallback: hardware-validated atomic scatter (R7 baseline)
        k_scatter<<<EE / 4, 256, 0, stream>>>(x, ei, agg);
    }
    int nblk = (NN + 31) / 32;
    k_gnn_ln<<<nblk, 256, 0, stream>>>(x, agg, Wn, Wr, bg, g1, be1, out);
    k_ffn_ln<<<nblk, 256, 0, stream>>>(out, W1, b1, W2, b2, g2, be2);
}

// Round 12
// 694.798 us; speedup vs baseline: 5.1747x; 1.4733x over previous
//
#include <hip/hip_runtime.h>

#define NN 50000
#define EE 800000
#define DD 256
#define DFFC 512
#define EPSF 1e-5f
#define CAP 64   // per-node edge bucket capacity; Poisson(16) => P(deg>64) ~ 1e-12

typedef __attribute__((ext_vector_type(8))) short short8;   // 8 bf16 = 4 VGPRs
typedef __attribute__((ext_vector_type(4))) float f32x4;    // MFMA C/D frag

// fp32 -> bf16 bit pattern, round-to-nearest-even
__device__ __forceinline__ unsigned short f2b(float f) {
    unsigned u = __float_as_uint(f);
    unsigned r = (u + 0x7FFFu + ((u >> 16) & 1u)) >> 16;
    return (unsigned short)r;
}

// ---------------------------------------------------------------------------
// K1a: bucket-fill.  pos = cnt[d]++; slot[d*CAP+pos] = s.  800K int atomics.
// ---------------------------------------------------------------------------
__global__ __launch_bounds__(256) void k_fill(const float* __restrict__ x,
                                              const int* __restrict__ ei,
                                              int* __restrict__ cnt,
                                              int* __restrict__ slot,
                                              float* __restrict__ agg) {
    int e = blockIdx.x * 256 + threadIdx.x;
    if (e >= EE) return;
    int s = ei[e];
    int d = ei[EE + e];
    int pos = atomicAdd(&cnt[d], 1);
    if (pos < CAP) {
        slot[d * CAP + pos] = s;
    } else {
        const float* xr = x + (size_t)s * DD;
        float* ar = agg + (size_t)d * DD;
        for (int j = 0; j < DD; ++j) unsafeAtomicAdd(ar + j, xr[j]);
    }
}

// ---------------------------------------------------------------------------
// K1b: gather-reduce.  One wave per dst node; lane owns cols c..c+3.
// ---------------------------------------------------------------------------
__global__ __launch_bounds__(256) void k_gather(const float* __restrict__ x,
                                                const int* __restrict__ cnt,
                                                const int* __restrict__ slot,
                                                float* __restrict__ agg) {
    int n = blockIdx.x * 4 + (threadIdx.x >> 6);
    int lane = threadIdx.x & 63;
    if (n >= NN) return;
    int deg = cnt[n];
    int m = deg < CAP ? deg : CAP;
    int c = lane * 4;
    float4 sum = {0.f, 0.f, 0.f, 0.f};
    const int* sl = slot + n * CAP;
#pragma unroll 2
    for (int i = 0; i < m; ++i) {
        int s = sl[i];
        float4 v = *reinterpret_cast<const float4*>(x + (size_t)s * DD + c);
        sum.x += v.x; sum.y += v.y; sum.z += v.z; sum.w += v.w;
    }
    float* out = agg + (size_t)n * DD + c;
    if (deg > CAP) {
        float4 b = *reinterpret_cast<const float4*>(out);
        sum.x += b.x; sum.y += b.y; sum.z += b.z; sum.w += b.w;
    }
    *reinterpret_cast<float4*>(out) = sum;
}

// ---------------------------------------------------------------------------
// K1 fallback (ws too small): atomic scatter
// ---------------------------------------------------------------------------
__global__ __launch_bounds__(256) void k_scatter(const float* __restrict__ x,
                                                 const int* __restrict__ ei,
                                                 float* __restrict__ agg) {
    int t = blockIdx.x * 256 + threadIdx.x;
    int e = t >> 6;
    int lane = t & 63;
    if (e >= EE) return;
    int s = ei[e];
    int d = ei[EE + e];
    float4 v = *reinterpret_cast<const float4*>(x + s * DD + lane * 4);
    float* o = agg + d * DD + lane * 4;
    unsafeAtomicAdd(o + 0, v.x);
    unsafeAtomicAdd(o + 1, v.y);
    unsafeAtomicAdd(o + 2, v.z);
    unsafeAtomicAdd(o + 3, v.w);
}

// ---------------------------------------------------------------------------
// Weight convert+transpose to bf16, k-major per output column:
//   bWcT[c][k] (k<256 -> Wn[k][c], else Wr[k-256][c]),  256x512
//   bW1T[c][k] = W1[k][c],  512x256
//   bW2T[c][k] = W2[k][c],  256x512
// ---------------------------------------------------------------------------
__global__ __launch_bounds__(256) void k_cvtw(
    const float* __restrict__ Wn, const float* __restrict__ Wr,
    const float* __restrict__ W1, const float* __restrict__ W2,
    unsigned short* __restrict__ bWcT, unsigned short* __restrict__ bW1T,
    unsigned short* __restrict__ bW2T) {
    int t = blockIdx.x * 256 + threadIdx.x;
    if (t < 131072) {                       // bWcT: c = t>>9, k = t&511
        int c = t >> 9, k = t & 511;
        float f = (k < 256) ? Wn[k * DD + c] : Wr[(k - 256) * DD + c];
        bWcT[t] = f2b(f);
    } else if (t < 262144) {                // bW1T: c = u>>8, k = u&255
        int u = t - 131072;
        int c = u >> 8, k = u & 255;
        bW1T[u] = f2b(W1[k * DFFC + c]);
    } else if (t < 393216) {                // bW2T: c = u>>9, k = u&511
        int u = t - 262144;
        int c = u >> 9, k = u & 511;
        bW2T[u] = f2b(W2[k * DD + c]);
    }
}

// ---------------------------------------------------------------------------
// K2 MFMA: h = LN(x + [agg|x] @ [Wn;Wr] + bg).  Block = 64 rows, 4 waves;
// wave = 16 rows x 256 cols (1 A-frag + 16 B-frags per K-step, K=512).
// LN is wave-local: row's 256 cols live in one 16-lane group x 16 nt frags.
// ---------------------------------------------------------------------------
__global__ __launch_bounds__(256) void k2_mfma(
    const float* __restrict__ agg, const float* __restrict__ x,
    const unsigned short* __restrict__ bWcT,
    const float* __restrict__ bg, const float* __restrict__ g1,
    const float* __restrict__ be1,
    float* __restrict__ h, unsigned short* __restrict__ hb) {
    const int tid = threadIdx.x;
    const int l = tid & 63, w = tid >> 6;
    const int lo = l & 15, g = l >> 4;
    const int gr0 = blockIdx.x * 64 + w * 16;
    int arow = gr0 + lo; if (arow >= NN) arow = NN - 1;
    const int ko = g * 8;

    f32x4 acc[16];
#pragma unroll
    for (int nt = 0; nt < 16; ++nt) acc[nt] = (f32x4){0.f, 0.f, 0.f, 0.f};

#pragma unroll 2
    for (int s = 0; s < 16; ++s) {
        const float* src = (s < 8) ? (agg + (size_t)arow * DD + s * 32 + ko)
                                   : (x + (size_t)arow * DD + (s - 8) * 32 + ko);
        float4 f0 = *reinterpret_cast<const float4*>(src);
        float4 f1 = *reinterpret_cast<const float4*>(src + 4);
        short8 a;
        a[0] = f2b(f0.x); a[1] = f2b(f0.y); a[2] = f2b(f0.z); a[3] = f2b(f0.w);
        a[4] = f2b(f1.x); a[5] = f2b(f1.y); a[6] = f2b(f1.z); a[7] = f2b(f1.w);
        const int kf = s * 32 + ko;         // fused k index 0..511
#pragma unroll
        for (int nt = 0; nt < 16; ++nt) {
            short8 b = *reinterpret_cast<const short8*>(
                bWcT + (((size_t)(nt * 16 + lo)) << 9) + kf);
            acc[nt] = __builtin_amdgcn_mfma_f32_16x16x32_bf16(a, b, acc[nt], 0, 0, 0);
        }
    }

    // epilogue: lane holds rows gr0+g*4+r (r=0..3), cols nt*16+lo
    float bgv[16], g1v[16], b1v[16];
#pragma unroll
    for (int nt = 0; nt < 16; ++nt) {
        int col = nt * 16 + lo;
        bgv[nt] = bg[col]; g1v[nt] = g1[col]; b1v[nt] = be1[col];
    }
#pragma unroll
    for (int r = 0; r < 4; ++r) {
        int grow = gr0 + g * 4 + r;
        bool valid = grow < NN;
        int rr = valid ? grow : NN - 1;
        float v[16]; float s = 0.f, q = 0.f;
#pragma unroll
        for (int nt = 0; nt < 16; ++nt) {
            float t = acc[nt][r] + bgv[nt] + x[(size_t)rr * DD + nt * 16 + lo];
            v[nt] = t; s += t; q += t * t;
        }
#pragma unroll
        for (int m = 8; m >= 1; m >>= 1) {
            s += __shfl_xor(s, m, 64);
            q += __shfl_xor(q, m, 64);
        }
        float mu = s * (1.f / 256.f);
        float var = q * (1.f / 256.f) - mu * mu;
        float rs = rsqrtf(var + EPSF);
        if (valid) {
#pragma unroll
            for (int nt = 0; nt < 16; ++nt) {
                float o = (v[nt] - mu) * rs * g1v[nt] + b1v[nt];
                size_t idx = (size_t)grow * DD + nt * 16 + lo;
                h[idx] = o;
                if (hb) hb[idx] = f2b(o);
            }
        }
    }
}

// ---------------------------------------------------------------------------
// K3 MFMA: out = LN(h + relu(h@W1+b1)@W2 + b2).  Same wave structure; DFF in
// 2 halves; relu(t) half-tile as bf16 in LDS (pitch 264 = 33*16B-aligned).
// ABF=1: A from bf16 h (hb); ABF=0: A from fp32 h with in-register cvt.
// ---------------------------------------------------------------------------
template <int ABF>
__global__ __launch_bounds__(256) void k3_mfma(
    float* __restrict__ hout, const unsigned short* __restrict__ hb,
    const unsigned short* __restrict__ bW1T, const unsigned short* __restrict__ bW2T,
    const float* __restrict__ b1, const float* __restrict__ b2,
    const float* __restrict__ g2, const float* __restrict__ be2) {
    __shared__ unsigned short tl[64][264];
    const int tid = threadIdx.x;
    const int l = tid & 63, w = tid >> 6;
    const int lo = l & 15, g = l >> 4;
    const int gr0 = blockIdx.x * 64 + w * 16;
    int arow = gr0 + lo; if (arow >= NN) arow = NN - 1;
    const int ko = g * 8;

    f32x4 acc2[16];
#pragma unroll
    for (int nt = 0; nt < 16; ++nt) acc2[nt] = (f32x4){0.f, 0.f, 0.f, 0.f};

    for (int half = 0; half < 2; ++half) {
        f32x4 acc1[16];
#pragma unroll
        for (int nt = 0; nt < 16; ++nt) acc1[nt] = (f32x4){0.f, 0.f, 0.f, 0.f};

        // ---- GEMM1 half: t = h @ W1[:, half*256 + (0..255)], K=256 ----
#pragma unroll 2
        for (int s = 0; s < 8; ++s) {
            short8 a;
            if (ABF) {
                a = *reinterpret_cast<const short8*>(
                    hb + (size_t)arow * DD + s * 32 + ko);
            } else {
                const float* src = hout + (size_t)arow * DD + s * 32 + ko;
                float4 f0 = *reinterpret_cast<const float4*>(src);
                float4 f1 = *reinterpret_cast<const float4*>(src + 4);
                a[0] = f2b(f0.x); a[1] = f2b(f0.y); a[2] = f2b(f0.z); a[3] = f2b(f0.w);
                a[4] = f2b(f1.x); a[5] = f2b(f1.y); a[6] = f2b(f1.z); a[7] = f2b(f1.w);
            }
            const int kk = s * 32 + ko;
#pragma unroll
            for (int nt = 0; nt < 16; ++nt) {
                int cdff = half * 256 + nt * 16 + lo;
                short8 b = *reinterpret_cast<const short8*>(
                    bW1T + (size_t)cdff * 256 + kk);
                acc1[nt] = __builtin_amdgcn_mfma_f32_16x16x32_bf16(a, b, acc1[nt], 0, 0, 0);
            }
        }
        __syncthreads();   // tl reuse boundary (half 1 overwrites half 0)
        // ---- bias + relu + cvt -> LDS t (wave-own rows) ----
#pragma unroll
        for (int nt = 0; nt < 16; ++nt) {
            float bv = b1[half * 256 + nt * 16 + lo];
#pragma unroll
            for (int r = 0; r < 4; ++r) {
                float t = fmaxf(acc1[nt][r] + bv, 0.f);
                tl[w * 16 + g * 4 + r][nt * 16 + lo] = f2b(t);
            }
        }
        __syncthreads();
        // ---- GEMM2 partial: acc2 += t_half @ W2[half*256.., :], K=256 ----
#pragma unroll 2
        for (int s = 0; s < 8; ++s) {
            short8 a = *reinterpret_cast<const short8*>(&tl[w * 16 + lo][s * 32 + ko]);
            const int kk2 = half * 256 + s * 32 + ko;
#pragma unroll
            for (int nt = 0; nt < 16; ++nt) {
                short8 b = *reinterpret_cast<const short8*>(
                    bW2T + (((size_t)(nt * 16 + lo)) << 9) + kk2);
                acc2[nt] = __builtin_amdgcn_mfma_f32_16x16x32_bf16(a, b, acc2[nt], 0, 0, 0);
            }
        }
    }

    // ---- epilogue: + b2 + h residual, LN2, store in place ----
    float b2v[16], g2v[16], e2v[16];
#pragma unroll
    for (int nt = 0; nt < 16; ++nt) {
        int col = nt * 16 + lo;
        b2v[nt] = b2[col]; g2v[nt] = g2[col]; e2v[nt] = be2[col];
    }
#pragma unroll
    for (int r = 0; r < 4; ++r) {
        int grow = gr0 + g * 4 + r;
        bool valid = grow < NN;
        int rr = valid ? grow : NN - 1;
        float v[16]; float s = 0.f, q = 0.f;
#pragma unroll
        for (int nt = 0; nt < 16; ++nt) {
            float t = acc2[nt][r] + b2v[nt] + hout[(size_t)rr * DD + nt * 16 + lo];
            v[nt] = t; s += t; q += t * t;
        }
#pragma unroll
        for (int m = 8; m >= 1; m >>= 1) {
            s += __shfl_xor(s, m, 64);
            q += __shfl_xor(q, m, 64);
        }
        float mu = s * (1.f / 256.f);
        float var = q * (1.f / 256.f) - mu * mu;
        float rs = rsqrtf(var + EPSF);
        if (valid) {
#pragma unroll
            for (int nt = 0; nt < 16; ++nt) {
                float o = (v[nt] - mu) * rs * g2v[nt] + e2v[nt];
                hout[(size_t)grow * DD + nt * 16 + lo] = o;
            }
        }
    }
}

// ---------------------------------------------------------------------------
// fp32 fallback GEMM kernels (R10 baseline, retained verbatim)
// ---------------------------------------------------------------------------
__global__ __launch_bounds__(256, 2) void k_gnn_ln(
    const float* __restrict__ x, const float* __restrict__ agg,
    const float* __restrict__ Wn, const float* __restrict__ Wr,
    const float* __restrict__ bg, const float* __restrict__ g1,
    const float* __restrict__ be1, float* __restrict__ h) {
    __shared__ float swn[32][256];
    __shared__ float swr[32][256];
    __shared__ float sta[32][36];
    __shared__ float stx[32][36];

    const int tid = threadIdx.x;
    const int lane = tid & 63;
    const int w = tid >> 6;
    const int c = lane * 4;
    const int r0 = w * 8;
    const int row0 = blockIdx.x * 32;

    float acc[8][4];
#pragma unroll
    for (int r = 0; r < 8; ++r)
#pragma unroll
        for (int j = 0; j < 4; ++j) acc[r][j] = 0.f;

    const int lr = tid >> 3;
    const int lk = (tid & 7) * 4;
    int lrow = row0 + lr;
    if (lrow >= NN) lrow = NN - 1;

    for (int k0 = 0; k0 < DD; k0 += 32) {
        __syncthreads();
#pragma unroll
        for (int i = 0; i < 8; ++i) {
            int flat = i * 1024 + tid * 4;
            int kk = flat >> 8, cc = flat & 255;
            *reinterpret_cast<float4*>(&swn[kk][cc]) =
                *reinterpret_cast<const float4*>(Wn + (k0 + kk) * DD + cc);
            *reinterpret_cast<float4*>(&swr[kk][cc]) =
                *reinterpret_cast<const float4*>(Wr + (k0 + kk) * DD + cc);
        }
        float4 va = *reinterpret_cast<const float4*>(agg + lrow * DD + k0 + lk);
        float4 vx = *reinterpret_cast<const float4*>(x + lrow * DD + k0 + lk);
        sta[lk + 0][lr] = va.x; sta[lk + 1][lr] = va.y;
        sta[lk + 2][lr] = va.z; sta[lk + 3][lr] = va.w;
        stx[lk + 0][lr] = vx.x; stx[lk + 1][lr] = vx.y;
        stx[lk + 2][lr] = vx.z; stx[lk + 3][lr] = vx.w;
        __syncthreads();
#pragma unroll 4
        for (int kk = 0; kk < 32; ++kk) {
            float4 wn4 = *reinterpret_cast<const float4*>(&swn[kk][c]);
            float4 wr4 = *reinterpret_cast<const float4*>(&swr[kk][c]);
            float4 a0 = *reinterpret_cast<const float4*>(&sta[kk][r0]);
            float4 a1 = *reinterpret_cast<const float4*>(&sta[kk][r0 + 4]);
            float4 b0 = *reinterpret_cast<const float4*>(&stx[kk][r0]);
            float4 b1 = *reinterpret_cast<const float4*>(&stx[kk][r0 + 4]);
            float aa[8] = {a0.x, a0.y, a0.z, a0.w, a1.x, a1.y, a1.z, a1.w};
            float xx[8] = {b0.x, b0.y, b0.z, b0.w, b1.x, b1.y, b1.z, b1.w};
#pragma unroll
            for (int r = 0; r < 8; ++r) {
                acc[r][0] += aa[r] * wn4.x + xx[r] * wr4.x;
                acc[r][1] += aa[r] * wn4.y + xx[r] * wr4.y;
                acc[r][2] += aa[r] * wn4.z + xx[r] * wr4.z;
                acc[r][3] += aa[r] * wn4.w + xx[r] * wr4.w;
            }
        }
    }

    float4 bgv = *reinterpret_cast<const float4*>(bg + c);
    float4 g1v = *reinterpret_cast<const float4*>(g1 + c);
    float4 b1v = *reinterpret_cast<const float4*>(be1 + c);
#pragma unroll
    for (int r = 0; r < 8; ++r) {
        int row = row0 + r0 + r;
        bool valid = row < NN;
        int rr = valid ? row : NN - 1;
        float4 xr = *reinterpret_cast<const float4*>(x + rr * DD + c);
        float v0 = acc[r][0] + bgv.x + xr.x;
        float v1 = acc[r][1] + bgv.y + xr.y;
        float v2 = acc[r][2] + bgv.z + xr.z;
        float v3 = acc[r][3] + bgv.w + xr.w;
        float s = v0 + v1 + v2 + v3;
        float q = v0 * v0 + v1 * v1 + v2 * v2 + v3 * v3;
#pragma unroll
        for (int off = 32; off >= 1; off >>= 1) {
            s += __shfl_xor(s, off, 64);
            q += __shfl_xor(q, off, 64);
        }
        float mu = s * (1.f / 256.f);
        float var = q * (1.f / 256.f) - mu * mu;
        float rs = rsqrtf(var + EPSF);
        float4 o;
        o.x = (v0 - mu) * rs * g1v.x + b1v.x;
        o.y = (v1 - mu) * rs * g1v.y + b1v.y;
        o.z = (v2 - mu) * rs * g1v.z + b1v.z;
        o.w = (v3 - mu) * rs * g1v.w + b1v.w;
        if (valid) *reinterpret_cast<float4*>(h + row * DD + c) = o;
    }
}

__global__ __launch_bounds__(256, 2) void k_ffn_ln(
    float* __restrict__ hout, const float* __restrict__ W1,
    const float* __restrict__ b1, const float* __restrict__ W2,
    const float* __restrict__ b2, const float* __restrict__ g2,
    const float* __restrict__ be2) {
    __shared__ float sw[32][256];
    __shared__ float sht[32][36];
    __shared__ float st[32][264];

    const int tid = threadIdx.x;
    const int lane = tid & 63;
    const int w = tid >> 6;
    const int c = lane * 4;
    const int r0 = w * 8;
    const int row0 = blockIdx.x * 32;
    const int lr = tid >> 3;
    const int lk = (tid & 7) * 4;
    int lrow = row0 + lr;
    if (lrow >= NN) lrow = NN - 1;

    float acc2[8][4];
#pragma unroll
    for (int r = 0; r < 8; ++r)
#pragma unroll
        for (int j = 0; j < 4; ++j) acc2[r][j] = 0.f;

    for (int half = 0; half < 2; ++half) {
        float acc1[8][4];
#pragma unroll
        for (int r = 0; r < 8; ++r)
#pragma unroll
            for (int j = 0; j < 4; ++j) acc1[r][j] = 0.f;

        for (int k0 = 0; k0 < DD; k0 += 32) {
            __syncthreads();
#pragma unroll
            for (int i = 0; i < 8; ++i) {
                int flat = i * 1024 + tid * 4;
                int kk = flat >> 8, cc = flat & 255;
                *reinterpret_cast<float4*>(&sw[kk][cc]) =
                    *reinterpret_cast<const float4*>(W1 + (k0 + kk) * DFFC + half * 256 + cc);
            }
            float4 vh = *reinterpret_cast<const float4*>(hout + lrow * DD + k0 + lk);
            sht[lk + 0][lr] = vh.x; sht[lk + 1][lr] = vh.y;
            sht[lk + 2][lr] = vh.z; sht[lk + 3][lr] = vh.w;
            __syncthreads();
#pragma unroll 4
            for (int kk = 0; kk < 32; ++kk) {
                float4 w4 = *reinterpret_cast<const float4*>(&sw[kk][c]);
                float4 a0 = *reinterpret_cast<const float4*>(&sht[kk][r0]);
                float4 a1 = *reinterpret_cast<const float4*>(&sht[kk][r0 + 4]);
                float aa[8] = {a0.x, a0.y, a0.z, a0.w, a1.x, a1.y, a1.z, a1.w};
#pragma unroll
                for (int r = 0; r < 8; ++r) {
                    acc1[r][0] += aa[r] * w4.x;
                    acc1[r][1] += aa[r] * w4.y;
                    acc1[r][2] += aa[r] * w4.z;
                    acc1[r][3] += aa[r] * w4.w;
                }
            }
        }
        __syncthreads();
        {
            float4 bv = *reinterpret_cast<const float4*>(b1 + half * 256 + c);
#pragma unroll
            for (int r = 0; r < 8; ++r) {
                float4 tv;
                tv.x = fmaxf(acc1[r][0] + bv.x, 0.f);
                tv.y = fmaxf(acc1[r][1] + bv.y, 0.f);
                tv.z = fmaxf(acc1[r][2] + bv.z, 0.f);
                tv.w = fmaxf(acc1[r][3] + bv.w, 0.f);
                *reinterpret_cast<float4*>(&st[r0 + r][c]) = tv;
            }
        }
        for (int k0 = 0; k0 < 256; k0 += 32) {
            __syncthreads();
#pragma unroll
            for (int i = 0; i < 8; ++i) {
                int flat = i * 1024 + tid * 4;
                int kk = flat >> 8, cc = flat & 255;
                *reinterpret_cast<float4*>(&sw[kk][cc]) =
                    *reinterpret_cast<const float4*>(W2 + (half * 256 + k0 + kk) * DD + cc);
            }
            __syncthreads();
#pragma unroll 2
            for (int kk4 = 0; kk4 < 32; kk4 += 4) {
                float4 w40 = *reinterpret_cast<const float4*>(&sw[kk4 + 0][c]);
                float4 w41 = *reinterpret_cast<const float4*>(&sw[kk4 + 1][c]);
                float4 w42 = *reinterpret_cast<const float4*>(&sw[kk4 + 2][c]);
                float4 w43 = *reinterpret_cast<const float4*>(&sw[kk4 + 3][c]);
#pragma unroll
                for (int r = 0; r < 8; ++r) {
                    float4 t4 = *reinterpret_cast<const float4*>(&st[r0 + r][k0 + kk4]);
                    acc2[r][0] += t4.x * w40.x + t4.y * w41.x + t4.z * w42.x + t4.w * w43.x;
                    acc2[r][1] += t4.x * w40.y + t4.y * w41.y + t4.z * w42.y + t4.w * w43.y;
                    acc2[r][2] += t4.x * w40.z + t4.y * w41.z + t4.z * w42.z + t4.w * w43.z;
                    acc2[r][3] += t4.x * w40.w + t4.y * w41.w + t4.z * w42.w + t4.w * w43.w;
                }
            }
        }
        __syncthreads();
    }

    float4 b2v = *reinterpret_cast<const float4*>(b2 + c);
    float4 g2v = *reinterpret_cast<const float4*>(g2 + c);
    float4 e2v = *reinterpret_cast<const float4*>(be2 + c);
#pragma unroll
    for (int r = 0; r < 8; ++r) {
        int row = row0 + r0 + r;
        bool valid = row < NN;
        int rr = valid ? row : NN - 1;
        float4 hr = *reinterpret_cast<const float4*>(hout + rr * DD + c);
        float v0 = acc2[r][0] + b2v.x + hr.x;
        float v1 = acc2[r][1] + b2v.y + hr.y;
        float v2 = acc2[r][2] + b2v.z + hr.z;
        float v3 = acc2[r][3] + b2v.w + hr.w;
        float s = v0 + v1 + v2 + v3;
        float q = v0 * v0 + v1 * v1 + v2 * v2 + v3 * v3;
#pragma unroll
        for (int off = 32; off >= 1; off >>= 1) {
            s += __shfl_xor(s, off, 64);
            q += __shfl_xor(q, off, 64);
        }
        float mu = s * (1.f / 256.f);
        float var = q * (1.f / 256.f) - mu * mu;
        float rs = rsqrtf(var + EPSF);
        float4 o;
        o.x = (v0 - mu) * rs * g2v.x + e2v.x;
        o.y = (v1 - mu) * rs * g2v.y + e2v.y;
        o.z = (v2 - mu) * rs * g2v.z + e2v.z;
        o.w = (v3 - mu) * rs * g2v.w + e2v.w;
        if (valid) *reinterpret_cast<float4*>(hout + row * DD + c) = o;
    }
}

// ---------------------------------------------------------------------------
extern "C" void kernel_launch(void* const* d_in, const int* in_sizes, int n_in,
                              void* d_out, int out_size, void* d_ws, size_t ws_size,
                              hipStream_t stream) {
    const float* x   = (const float*)d_in[0];
    const int*   ei  = (const int*)d_in[1];
    const float* Wn  = (const float*)d_in[2];
    const float* Wr  = (const float*)d_in[3];
    const float* bg  = (const float*)d_in[4];
    const float* W1  = (const float*)d_in[5];
    const float* b1  = (const float*)d_in[6];
    const float* W2  = (const float*)d_in[7];
    const float* b2  = (const float*)d_in[8];
    const float* g1  = (const float*)d_in[9];
    const float* be1 = (const float*)d_in[10];
    const float* g2  = (const float*)d_in[11];
    const float* be2 = (const float*)d_in[12];
    float* out = (float*)d_out;

    const size_t aggB  = (size_t)NN * DD * sizeof(float);       // 51.2 MB
    const size_t cntB  = (size_t)NN * sizeof(int);              // 0.2 MB
    const size_t slotB = (size_t)NN * CAP * sizeof(int);        // 12.8 MB
    const size_t wB    = (size_t)3 * 131072 * sizeof(unsigned short); // 768 KB
    const size_t hbB   = (size_t)NN * DD * sizeof(unsigned short);    // 25.6 MB

    char* p = (char*)d_ws;
    float* agg = (float*)p;            p += aggB;
    int* cnt   = (int*)p;              p += cntB;
    int* slot  = (int*)p;              p += slotB;
    const size_t baseUsed = aggB + cntB + slotB;                // 64.2 MB

    const bool csr_ok  = ws_size >= baseUsed;
    const bool mfma_ok = ws_size >= baseUsed + wB;              // ~65.0 MB
    const bool hb_ok   = ws_size >= baseUsed + wB + hbB;        // ~90.6 MB

    hipMemsetAsync(agg, 0, aggB, stream);
    if (csr_ok) {
        hipMemsetAsync(cnt, 0, cntB, stream);
        k_fill<<<(EE + 255) / 256, 256, 0, stream>>>(x, ei, cnt, slot, agg);
        k_gather<<<(NN + 3) / 4, 256, 0, stream>>>(x, cnt, slot, agg);
    } else {
        k_scatter<<<EE / 4, 256, 0, stream>>>(x, ei, agg);
    }

    if (mfma_ok) {
        unsigned short* bWcT = (unsigned short*)p;  p += 131072 * 2;
        unsigned short* bW1T = (unsigned short*)p;  p += 131072 * 2;
        unsigned short* bW2T = (unsigned short*)p;  p += 131072 * 2;
        unsigned short* hb = hb_ok ? (unsigned short*)p : nullptr;
        k_cvtw<<<1536, 256, 0, stream>>>(Wn, Wr, W1, W2, bWcT, bW1T, bW2T);
        int g64 = (NN + 63) / 64;   // 782
        k2_mfma<<<g64, 256, 0, stream>>>(agg, x, bWcT, bg, g1, be1, out, hb);
        if (hb) k3_mfma<1><<<g64, 256, 0, stream>>>(out, hb, bW1T, bW2T, b1, b2, g2, be2);
        else    k3_mfma<0><<<g64, 256, 0, stream>>>(out, nullptr, bW1T, bW2T, b1, b2, g2, be2);
    } else {
        int nblk = (NN + 31) / 32;
        k_gnn_ln<<<nblk, 256, 0, stream>>>(x, agg, Wn, Wr, bg, g1, be1, out);
        k_ffn_ln<<<nblk, 256, 0, stream>>>(out, W1, b1, W2, b2, g2, be2);
    }
}

// Round 14
// 521.079 us; speedup vs baseline: 6.8998x; 1.3334x over previous
//
#include <hip/hip_runtime.h>

#define NN 50000
#define EE 800000
#define DD 256
#define DFFC 512
#define EPSF 1e-5f
#define CAP 64   // per-node edge bucket capacity; Poisson(16) => P(deg>64) ~ 1e-12

typedef __attribute__((ext_vector_type(8))) short short8;   // 8 bf16 = 4 VGPRs
typedef __attribute__((ext_vector_type(4))) float f32x4;    // MFMA C/D frag

// fp32 -> bf16 bit pattern, round-to-nearest-even
__device__ __forceinline__ unsigned short f2b(float f) {
    unsigned u = __float_as_uint(f);
    unsigned r = (u + 0x7FFFu + ((u >> 16) & 1u)) >> 16;
    return (unsigned short)r;
}

// ---------------------------------------------------------------------------
// K1a: bucket-fill.  pos = cnt[d]++; slot[d*CAP+pos] = s.  800K int atomics.
// ---------------------------------------------------------------------------
__global__ __launch_bounds__(256) void k_fill(const float* __restrict__ x,
                                              const int* __restrict__ ei,
                                              int* __restrict__ cnt,
                                              int* __restrict__ slot,
                                              float* __restrict__ agg) {
    int e = blockIdx.x * 256 + threadIdx.x;
    if (e >= EE) return;
    int s = ei[e];
    int d = ei[EE + e];
    int pos = atomicAdd(&cnt[d], 1);
    if (pos < CAP) {
        slot[d * CAP + pos] = s;
    } else {
        const float* xr = x + (size_t)s * DD;
        float* ar = agg + (size_t)d * DD;
        for (int j = 0; j < DD; ++j) unsafeAtomicAdd(ar + j, xr[j]);
    }
}

// ---------------------------------------------------------------------------
// K1b: gather-reduce.  One wave per dst node; lane owns cols c..c+3.
// ---------------------------------------------------------------------------
__global__ __launch_bounds__(256) void k_gather(const float* __restrict__ x,
                                                const int* __restrict__ cnt,
                                                const int* __restrict__ slot,
                                                float* __restrict__ agg) {
    int n = blockIdx.x * 4 + (threadIdx.x >> 6);
    int lane = threadIdx.x & 63;
    if (n >= NN) return;
    int deg = cnt[n];
    int m = deg < CAP ? deg : CAP;
    int c = lane * 4;
    float4 sum = {0.f, 0.f, 0.f, 0.f};
    const int* sl = slot + n * CAP;
#pragma unroll 2
    for (int i = 0; i < m; ++i) {
        int s = sl[i];
        float4 v = *reinterpret_cast<const float4*>(x + (size_t)s * DD + c);
        sum.x += v.x; sum.y += v.y; sum.z += v.z; sum.w += v.w;
    }
    float* out = agg + (size_t)n * DD + c;
    if (deg > CAP) {
        float4 b = *reinterpret_cast<const float4*>(out);
        sum.x += b.x; sum.y += b.y; sum.z += b.z; sum.w += b.w;
    }
    *reinterpret_cast<float4*>(out) = sum;
}

// ---------------------------------------------------------------------------
// K1 fallback (ws too small): atomic scatter
// ---------------------------------------------------------------------------
__global__ __launch_bounds__(256) void k_scatter(const float* __restrict__ x,
                                                 const int* __restrict__ ei,
                                                 float* __restrict__ agg) {
    int t = blockIdx.x * 256 + threadIdx.x;
    int e = t >> 6;
    int lane = t & 63;
    if (e >= EE) return;
    int s = ei[e];
    int d = ei[EE + e];
    float4 v = *reinterpret_cast<const float4*>(x + s * DD + lane * 4);
    float* o = agg + d * DD + lane * 4;
    unsafeAtomicAdd(o + 0, v.x);
    unsafeAtomicAdd(o + 1, v.y);
    unsafeAtomicAdd(o + 2, v.z);
    unsafeAtomicAdd(o + 3, v.w);
}

// ---------------------------------------------------------------------------
// Weight convert+transpose to bf16, k-major per output column:
//   bWcT[c][k] (k<256 -> Wn[k][c], else Wr[k-256][c]),  256x512
//   bW1T[c][k] = W1[k][c],  512x256
//   bW2T[c][k] = W2[k][c],  256x512
// ---------------------------------------------------------------------------
__global__ __launch_bounds__(256) void k_cvtw(
    const float* __restrict__ Wn, const float* __restrict__ Wr,
    const float* __restrict__ W1, const float* __restrict__ W2,
    unsigned short* __restrict__ bWcT, unsigned short* __restrict__ bW1T,
    unsigned short* __restrict__ bW2T) {
    int t = blockIdx.x * 256 + threadIdx.x;
    if (t < 131072) {                       // bWcT: c = t>>9, k = t&511
        int c = t >> 9, k = t & 511;
        float f = (k < 256) ? Wn[k * DD + c] : Wr[(k - 256) * DD + c];
        bWcT[t] = f2b(f);
    } else if (t < 262144) {                // bW1T: c = u>>8, k = u&255
        int u = t - 131072;
        int c = u >> 8, k = u & 255;
        bW1T[u] = f2b(W1[k * DFFC + c]);
    } else if (t < 393216) {                // bW2T: c = u>>9, k = u&511
        int u = t - 262144;
        int c = u >> 9, k = u & 511;
        bW2T[u] = f2b(W2[k * DD + c]);
    }
}

// ---------------------------------------------------------------------------
// K2 MFMA (R12: LDS-staged B + hoisted A).  h = LN(x + [agg|x]@[Wn;Wr] + bg).
// Block = 64 rows, 4 waves; wave = 16 rows x 256 cols.  K=512 in 16 chunks;
// per chunk all 256 threads stage the 16KB B-slab to LDS (sb pitch 40 shorts
// = 80B, 16B-aligned, ~2-way bank aliasing = free).
// ---------------------------------------------------------------------------
__global__ __launch_bounds__(256) void k2_mfma(
    const float* __restrict__ agg, const float* __restrict__ x,
    const unsigned short* __restrict__ bWcT,
    const float* __restrict__ bg, const float* __restrict__ g1,
    const float* __restrict__ be1,
    float* __restrict__ h, unsigned short* __restrict__ hb) {
    __shared__ unsigned short sb[256][40];
    const int tid = threadIdx.x;
    const int l = tid & 63, w = tid >> 6;
    const int lo = l & 15, g = l >> 4;
    const int gr0 = blockIdx.x * 64 + w * 16;
    int arow = gr0 + lo; if (arow >= NN) arow = NN - 1;
    const int ko = g * 8;

    // hoist all 16 A-fragments (K=512): s<8 from agg, s>=8 from x
    short8 af[16];
#pragma unroll
    for (int s = 0; s < 16; ++s) {
        const float* src = (s < 8) ? (agg + (size_t)arow * DD + s * 32 + ko)
                                   : (x + (size_t)arow * DD + (s - 8) * 32 + ko);
        float4 f0 = *reinterpret_cast<const float4*>(src);
        float4 f1 = *reinterpret_cast<const float4*>(src + 4);
        short8 a;
        a[0] = f2b(f0.x); a[1] = f2b(f0.y); a[2] = f2b(f0.z); a[3] = f2b(f0.w);
        a[4] = f2b(f1.x); a[5] = f2b(f1.y); a[6] = f2b(f1.z); a[7] = f2b(f1.w);
        af[s] = a;
    }

    f32x4 acc[16];
#pragma unroll
    for (int nt = 0; nt < 16; ++nt) acc[nt] = (f32x4){0.f, 0.f, 0.f, 0.f};

#pragma unroll
    for (int s = 0; s < 16; ++s) {
        __syncthreads();
        {   // stage B chunk: col=tid, 32 k contiguous (64B) as 4x16B
            const unsigned short* src = bWcT + (size_t)tid * 512 + s * 32;
#pragma unroll
            for (int u = 0; u < 4; ++u)
                *reinterpret_cast<short8*>(&sb[tid][u * 8]) =
                    *reinterpret_cast<const short8*>(src + u * 8);
        }
        __syncthreads();
#pragma unroll
        for (int nt = 0; nt < 16; ++nt) {
            short8 b = *reinterpret_cast<const short8*>(&sb[nt * 16 + lo][ko]);
            acc[nt] = __builtin_amdgcn_mfma_f32_16x16x32_bf16(af[s], b, acc[nt], 0, 0, 0);
        }
    }

    // epilogue: lane holds rows gr0+g*4+r (r=0..3), cols nt*16+lo
    float bgv[16], g1v[16], b1v[16];
#pragma unroll
    for (int nt = 0; nt < 16; ++nt) {
        int col = nt * 16 + lo;
        bgv[nt] = bg[col]; g1v[nt] = g1[col]; b1v[nt] = be1[col];
    }
#pragma unroll
    for (int r = 0; r < 4; ++r) {
        int grow = gr0 + g * 4 + r;
        bool valid = grow < NN;
        int rr = valid ? grow : NN - 1;
        float v[16]; float s = 0.f, q = 0.f;
#pragma unroll
        for (int nt = 0; nt < 16; ++nt) {
            float t = acc[nt][r] + bgv[nt] + x[(size_t)rr * DD + nt * 16 + lo];
            v[nt] = t; s += t; q += t * t;
        }
#pragma unroll
        for (int m = 8; m >= 1; m >>= 1) {
            s += __shfl_xor(s, m, 64);
            q += __shfl_xor(q, m, 64);
        }
        float mu = s * (1.f / 256.f);
        float var = q * (1.f / 256.f) - mu * mu;
        float rs = rsqrtf(var + EPSF);
        if (valid) {
#pragma unroll
            for (int nt = 0; nt < 16; ++nt) {
                float o = (v[nt] - mu) * rs * g1v[nt] + b1v[nt];
                size_t idx = (size_t)grow * DD + nt * 16 + lo;
                h[idx] = o;
                if (hb) hb[idx] = f2b(o);
            }
        }
    }
}

// ---------------------------------------------------------------------------
// K3 MFMA (R12: LDS-staged B + hoisted A).  out = LN(h + relu(h@W1+b1)@W2 + b2).
// ---------------------------------------------------------------------------
template <int ABF>
__global__ __launch_bounds__(256) void k3_mfma(
    float* __restrict__ hout, const unsigned short* __restrict__ hb,
    const unsigned short* __restrict__ bW1T, const unsigned short* __restrict__ bW2T,
    const float* __restrict__ b1, const float* __restrict__ b2,
    const float* __restrict__ g2, const float* __restrict__ be2) {
    __shared__ unsigned short tl[64][264];   // relu(t) tile, pitch 528B = 33x16
    __shared__ unsigned short sb[256][40];   // staged B chunk
    const int tid = threadIdx.x;
    const int l = tid & 63, w = tid >> 6;
    const int lo = l & 15, g = l >> 4;
    const int gr0 = blockIdx.x * 64 + w * 16;
    int arow = gr0 + lo; if (arow >= NN) arow = NN - 1;
    const int ko = g * 8;

    // hoist the 8 A-fragments of h[arow] (K=256, shared by both DFF halves)
    short8 af[8];
#pragma unroll
    for (int s = 0; s < 8; ++s) {
        if (ABF) {
            af[s] = *reinterpret_cast<const short8*>(
                hb + (size_t)arow * DD + s * 32 + ko);
        } else {
            const float* src = hout + (size_t)arow * DD + s * 32 + ko;
            float4 f0 = *reinterpret_cast<const float4*>(src);
            float4 f1 = *reinterpret_cast<const float4*>(src + 4);
            short8 a;
            a[0] = f2b(f0.x); a[1] = f2b(f0.y); a[2] = f2b(f0.z); a[3] = f2b(f0.w);
            a[4] = f2b(f1.x); a[5] = f2b(f1.y); a[6] = f2b(f1.z); a[7] = f2b(f1.w);
            af[s] = a;
        }
    }

    f32x4 acc2[16];
#pragma unroll
    for (int nt = 0; nt < 16; ++nt) acc2[nt] = (f32x4){0.f, 0.f, 0.f, 0.f};

    for (int half = 0; half < 2; ++half) {
        f32x4 acc1[16];
#pragma unroll
        for (int nt = 0; nt < 16; ++nt) acc1[nt] = (f32x4){0.f, 0.f, 0.f, 0.f};

        // ---- GEMM1 half: t = h @ W1[:, half*256 + (0..255)], K=256 ----
#pragma unroll
        for (int s = 0; s < 8; ++s) {
            __syncthreads();
            {   // stage: col=tid of this half's 256 W1 columns
                const unsigned short* src =
                    bW1T + (size_t)(half * 256 + tid) * 256 + s * 32;
#pragma unroll
                for (int u = 0; u < 4; ++u)
                    *reinterpret_cast<short8*>(&sb[tid][u * 8]) =
                        *reinterpret_cast<const short8*>(src + u * 8);
            }
            __syncthreads();
#pragma unroll
            for (int nt = 0; nt < 16; ++nt) {
                short8 b = *reinterpret_cast<const short8*>(&sb[nt * 16 + lo][ko]);
                acc1[nt] = __builtin_amdgcn_mfma_f32_16x16x32_bf16(af[s], b, acc1[nt], 0, 0, 0);
            }
        }
        __syncthreads();   // tl reuse boundary (half 1 overwrites half 0)
        // ---- bias + relu + cvt -> LDS t (wave-own rows) ----
#pragma unroll
        for (int nt = 0; nt < 16; ++nt) {
            float bv = b1[half * 256 + nt * 16 + lo];
#pragma unroll
            for (int r = 0; r < 4; ++r) {
                float t = fmaxf(acc1[nt][r] + bv, 0.f);
                tl[w * 16 + g * 4 + r][nt * 16 + lo] = f2b(t);
            }
        }
        __syncthreads();
        // ---- GEMM2 partial: acc2 += t_half @ W2[half*256.., :], K=256 ----
#pragma unroll
        for (int s = 0; s < 8; ++s) {
            __syncthreads();
            {   // stage: col=tid output column, k = half*256 + s*32 ..
                const unsigned short* src =
                    bW2T + (size_t)tid * 512 + half * 256 + s * 32;
#pragma unroll
                for (int u = 0; u < 4; ++u)
                    *reinterpret_cast<short8*>(&sb[tid][u * 8]) =
                        *reinterpret_cast<const short8*>(src + u * 8);
            }
            __syncthreads();
            short8 a = *reinterpret_cast<const short8*>(&tl[w * 16 + lo][s * 32 + ko]);
#pragma unroll
            for (int nt = 0; nt < 16; ++nt) {
                short8 b = *reinterpret_cast<const short8*>(&sb[nt * 16 + lo][ko]);
                acc2[nt] = __builtin_amdgcn_mfma_f32_16x16x32_bf16(a, b, acc2[nt], 0, 0, 0);
            }
        }
    }

    // ---- epilogue: + b2 + h residual, LN2, store in place ----
    float b2v[16], g2v[16], e2v[16];
#pragma unroll
    for (int nt = 0; nt < 16; ++nt) {
        int col = nt * 16 + lo;
        b2v[nt] = b2[col]; g2v[nt] = g2[col]; e2v[nt] = be2[col];
    }
#pragma unroll
    for (int r = 0; r < 4; ++r) {
        int grow = gr0 + g * 4 + r;
        bool valid = grow < NN;
        int rr = valid ? grow : NN - 1;
        float v[16]; float s = 0.f, q = 0.f;
#pragma unroll
        for (int nt = 0; nt < 16; ++nt) {
            float t = acc2[nt][r] + b2v[nt] + hout[(size_t)rr * DD + nt * 16 + lo];
            v[nt] = t; s += t; q += t * t;
        }
#pragma unroll
        for (int m = 8; m >= 1; m >>= 1) {
            s += __shfl_xor(s, m, 64);
            q += __shfl_xor(q, m, 64);
        }
        float mu = s * (1.f / 256.f);
        float var = q * (1.f / 256.f) - mu * mu;
        float rs = rsqrtf(var + EPSF);
        if (valid) {
#pragma unroll
            for (int nt = 0; nt < 16; ++nt) {
                float o = (v[nt] - mu) * rs * g2v[nt] + e2v[nt];
                hout[(size_t)grow * DD + nt * 16 + lo] = o;
            }
        }
    }
}

// ---------------------------------------------------------------------------
// fp32 fallback GEMM kernels (R10 baseline, retained verbatim)
// ---------------------------------------------------------------------------
__global__ __launch_bounds__(256, 2) void k_gnn_ln(
    const float* __restrict__ x, const float* __restrict__ agg,
    const float* __restrict__ Wn, const float* __restrict__ Wr,
    const float* __restrict__ bg, const float* __restrict__ g1,
    const float* __restrict__ be1, float* __restrict__ h) {
    __shared__ float swn[32][256];
    __shared__ float swr[32][256];
    __shared__ float sta[32][36];
    __shared__ float stx[32][36];

    const int tid = threadIdx.x;
    const int lane = tid & 63;
    const int w = tid >> 6;
    const int c = lane * 4;
    const int r0 = w * 8;
    const int row0 = blockIdx.x * 32;

    float acc[8][4];
#pragma unroll
    for (int r = 0; r < 8; ++r)
#pragma unroll
        for (int j = 0; j < 4; ++j) acc[r][j] = 0.f;

    const int lr = tid >> 3;
    const int lk = (tid & 7) * 4;
    int lrow = row0 + lr;
    if (lrow >= NN) lrow = NN - 1;

    for (int k0 = 0; k0 < DD; k0 += 32) {
        __syncthreads();
#pragma unroll
        for (int i = 0; i < 8; ++i) {
            int flat = i * 1024 + tid * 4;
            int kk = flat >> 8, cc = flat & 255;
            *reinterpret_cast<float4*>(&swn[kk][cc]) =
                *reinterpret_cast<const float4*>(Wn + (k0 + kk) * DD + cc);
            *reinterpret_cast<float4*>(&swr[kk][cc]) =
                *reinterpret_cast<const float4*>(Wr + (k0 + kk) * DD + cc);
        }
        float4 va = *reinterpret_cast<const float4*>(agg + lrow * DD + k0 + lk);
        float4 vx = *reinterpret_cast<const float4*>(x + lrow * DD + k0 + lk);
        sta[lk + 0][lr] = va.x; sta[lk + 1][lr] = va.y;
        sta[lk + 2][lr] = va.z; sta[lk + 3][lr] = va.w;
        stx[lk + 0][lr] = vx.x; stx[lk + 1][lr] = vx.y;
        stx[lk + 2][lr] = vx.z; stx[lk + 3][lr] = vx.w;
        __syncthreads();
#pragma unroll 4
        for (int kk = 0; kk < 32; ++kk) {
            float4 wn4 = *reinterpret_cast<const float4*>(&swn[kk][c]);
            float4 wr4 = *reinterpret_cast<const float4*>(&swr[kk][c]);
            float4 a0 = *reinterpret_cast<const float4*>(&sta[kk][r0]);
            float4 a1 = *reinterpret_cast<const float4*>(&sta[kk][r0 + 4]);
            float4 b0 = *reinterpret_cast<const float4*>(&stx[kk][r0]);
            float4 b1 = *reinterpret_cast<const float4*>(&stx[kk][r0 + 4]);
            float aa[8] = {a0.x, a0.y, a0.z, a0.w, a1.x, a1.y, a1.z, a1.w};
            float xx[8] = {b0.x, b0.y, b0.z, b0.w, b1.x, b1.y, b1.z, b1.w};
#pragma unroll
            for (int r = 0; r < 8; ++r) {
                acc[r][0] += aa[r] * wn4.x + xx[r] * wr4.x;
                acc[r][1] += aa[r] * wn4.y + xx[r] * wr4.y;
                acc[r][2] += aa[r] * wn4.z + xx[r] * wr4.z;
                acc[r][3] += aa[r] * wn4.w + xx[r] * wr4.w;
            }
        }
    }

    float4 bgv = *reinterpret_cast<const float4*>(bg + c);
    float4 g1v = *reinterpret_cast<const float4*>(g1 + c);
    float4 b1v = *reinterpret_cast<const float4*>(be1 + c);
#pragma unroll
    for (int r = 0; r < 8; ++r) {
        int row = row0 + r0 + r;
        bool valid = row < NN;
        int rr = valid ? row : NN - 1;
        float4 xr = *reinterpret_cast<const float4*>(x + rr * DD + c);
        float v0 = acc[r][0] + bgv.x + xr.x;
        float v1 = acc[r][1] + bgv.y + xr.y;
        float v2 = acc[r][2] + bgv.z + xr.z;
        float v3 = acc[r][3] + bgv.w + xr.w;
        float s = v0 + v1 + v2 + v3;
        float q = v0 * v0 + v1 * v1 + v2 * v2 + v3 * v3;
#pragma unroll
        for (int off = 32; off >= 1; off >>= 1) {
            s += __shfl_xor(s, off, 64);
            q += __shfl_xor(q, off, 64);
        }
        float mu = s * (1.f / 256.f);
        float var = q * (1.f / 256.f) - mu * mu;
        float rs = rsqrtf(var + EPSF);
        float4 o;
        o.x = (v0 - mu) * rs * g1v.x + b1v.x;
        o.y = (v1 - mu) * rs * g1v.y + b1v.y;
        o.z = (v2 - mu) * rs * g1v.z + b1v.z;
        o.w = (v3 - mu) * rs * g1v.w + b1v.w;
        if (valid) *reinterpret_cast<float4*>(h + row * DD + c) = o;
    }
}

__global__ __launch_bounds__(256, 2) void k_ffn_ln(
    float* __restrict__ hout, const float* __restrict__ W1,
    const float* __restrict__ b1, const float* __restrict__ W2,
    const float* __restrict__ b2, const float* __restrict__ g2,
    const float* __restrict__ be2) {
    __shared__ float sw[32][256];
    __shared__ float sht[32][36];
    __shared__ float st[32][264];

    const int tid = threadIdx.x;
    const int lane = tid & 63;
    const int w = tid >> 6;
    const int c = lane * 4;
    const int r0 = w * 8;
    const int row0 = blockIdx.x * 32;
    const int lr = tid >> 3;
    const int lk = (tid & 7) * 4;
    int lrow = row0 + lr;
    if (lrow >= NN) lrow = NN - 1;

    float acc2[8][4];
#pragma unroll
    for (int r = 0; r < 8; ++r)
#pragma unroll
        for (int j = 0; j < 4; ++j) acc2[r][j] = 0.f;

    for (int half = 0; half < 2; ++half) {
        float acc1[8][4];
#pragma unroll
        for (int r = 0; r < 8; ++r)
#pragma unroll
            for (int j = 0; j < 4; ++j) acc1[r][j] = 0.f;

        for (int k0 = 0; k0 < DD; k0 += 32) {
            __syncthreads();
#pragma unroll
            for (int i = 0; i < 8; ++i) {
                int flat = i * 1024 + tid * 4;
                int kk = flat >> 8, cc = flat & 255;
                *reinterpret_cast<float4*>(&sw[kk][cc]) =
                    *reinterpret_cast<const float4*>(W1 + (k0 + kk) * DFFC + half * 256 + cc);
            }
            float4 vh = *reinterpret_cast<const float4*>(hout + lrow * DD + k0 + lk);
            sht[lk + 0][lr] = vh.x; sht[lk + 1][lr] = vh.y;
            sht[lk + 2][lr] = vh.z; sht[lk + 3][lr] = vh.w;
            __syncthreads();
#pragma unroll 4
            for (int kk = 0; kk < 32; ++kk) {
                float4 w4 = *reinterpret_cast<const float4*>(&sw[kk][c]);
                float4 a0 = *reinterpret_cast<const float4*>(&sht[kk][r0]);
                float4 a1 = *reinterpret_cast<const float4*>(&sht[kk][r0 + 4]);
                float aa[8] = {a0.x, a0.y, a0.z, a0.w, a1.x, a1.y, a1.z, a1.w};
#pragma unroll
                for (int r = 0; r < 8; ++r) {
                    acc1[r][0] += aa[r] * w4.x;
                    acc1[r][1] += aa[r] * w4.y;
                    acc1[r][2] += aa[r] * w4.z;
                    acc1[r][3] += aa[r] * w4.w;
                }
            }
        }
        __syncthreads();
        {
            float4 bv = *reinterpret_cast<const float4*>(b1 + half * 256 + c);
#pragma unroll
            for (int r = 0; r < 8; ++r) {
                float4 tv;
                tv.x = fmaxf(acc1[r][0] + bv.x, 0.f);
                tv.y = fmaxf(acc1[r][1] + bv.y, 0.f);
                tv.z = fmaxf(acc1[r][2] + bv.z, 0.f);
                tv.w = fmaxf(acc1[r][3] + bv.w, 0.f);
                *reinterpret_cast<float4*>(&st[r0 + r][c]) = tv;
            }
        }
        for (int k0 = 0; k0 < 256; k0 += 32) {
            __syncthreads();
#pragma unroll
            for (int i = 0; i < 8; ++i) {
                int flat = i * 1024 + tid * 4;
                int kk = flat >> 8, cc = flat & 255;
                *reinterpret_cast<float4*>(&sw[kk][cc]) =
                    *reinterpret_cast<const float4*>(W2 + (half * 256 + k0 + kk) * DD + cc);
            }
            __syncthreads();
#pragma unroll 2
            for (int kk4 = 0; kk4 < 32; kk4 += 4) {
                float4 w40 = *reinterpret_cast<const float4*>(&sw[kk4 + 0][c]);
                float4 w41 = *reinterpret_cast<const float4*>(&sw[kk4 + 1][c]);
                float4 w42 = *reinterpret_cast<const float4*>(&sw[kk4 + 2][c]);
                float4 w43 = *reinterpret_cast<const float4*>(&sw[kk4 + 3][c]);
#pragma unroll
                for (int r = 0; r < 8; ++r) {
                    float4 t4 = *reinterpret_cast<const float4*>(&st[r0 + r][k0 + kk4]);
                    acc2[r][0] += t4.x * w40.x + t4.y * w41.x + t4.z * w42.x + t4.w * w43.x;
                    acc2[r][1] += t4.x * w40.y + t4.y * w41.y + t4.z * w42.y + t4.w * w43.y;
                    acc2[r][2] += t4.x * w40.z + t4.y * w41.z + t4.z * w42.z + t4.w * w43.z;
                    acc2[r][3] += t4.x * w40.w + t4.y * w41.w + t4.z * w42.w + t4.w * w43.w;
                }
            }
        }
        __syncthreads();
    }

    float4 b2v = *reinterpret_cast<const float4*>(b2 + c);
    float4 g2v = *reinterpret_cast<const float4*>(g2 + c);
    float4 e2v = *reinterpret_cast<const float4*>(be2 + c);
#pragma unroll
    for (int r = 0; r < 8; ++r) {
        int row = row0 + r0 + r;
        bool valid = row < NN;
        int rr = valid ? row : NN - 1;
        float4 hr = *reinterpret_cast<const float4*>(hout + rr * DD + c);
        float v0 = acc2[r][0] + b2v.x + hr.x;
        float v1 = acc2[r][1] + b2v.y + hr.y;
        float v2 = acc2[r][2] + b2v.z + hr.z;
        float v3 = acc2[r][3] + b2v.w + hr.w;
        float s = v0 + v1 + v2 + v3;
        float q = v0 * v0 + v1 * v1 + v2 * v2 + v3 * v3;
#pragma unroll
        for (int off = 32; off >= 1; off >>= 1) {
            s += __shfl_xor(s, off, 64);
            q += __shfl_xor(q, off, 64);
        }
        float mu = s * (1.f / 256.f);
        float var = q * (1.f / 256.f) - mu * mu;
        float rs = rsqrtf(var + EPSF);
        float4 o;
        o.x = (v0 - mu) * rs * g2v.x + e2v.x;
        o.y = (v1 - mu) * rs * g2v.y + e2v.y;
        o.z = (v2 - mu) * rs * g2v.z + e2v.z;
        o.w = (v3 - mu) * rs * g2v.w + e2v.w;
        if (valid) *reinterpret_cast<float4*>(hout + row * DD + c) = o;
    }
}

// ---------------------------------------------------------------------------
extern "C" void kernel_launch(void* const* d_in, const int* in_sizes, int n_in,
                              void* d_out, int out_size, void* d_ws, size_t ws_size,
                              hipStream_t stream) {
    const float* x   = (const float*)d_in[0];
    const int*   ei  = (const int*)d_in[1];
    const float* Wn  = (const float*)d_in[2];
    const float* Wr  = (const float*)d_in[3];
    const float* bg  = (const float*)d_in[4];
    const float* W1  = (const float*)d_in[5];
    const float* b1  = (const float*)d_in[6];
    const float* W2  = (const float*)d_in[7];
    const float* b2  = (const float*)d_in[8];
    const float* g1  = (const float*)d_in[9];
    const float* be1 = (const float*)d_in[10];
    const float* g2  = (const float*)d_in[11];
    const float* be2 = (const float*)d_in[12];
    float* out = (float*)d_out;

    const size_t aggB  = (size_t)NN * DD * sizeof(float);       // 51.2 MB
    const size_t cntB  = (size_t)NN * sizeof(int);              // 0.2 MB
    const size_t slotB = (size_t)NN * CAP * sizeof(int);        // 12.8 MB
    const size_t wB    = (size_t)3 * 131072 * sizeof(unsigned short); // 768 KB
    const size_t hbB   = (size_t)NN * DD * sizeof(unsigned short);    // 25.6 MB

    char* p = (char*)d_ws;
    float* agg = (float*)p;            p += aggB;
    int* cnt   = (int*)p;              p += cntB;
    int* slot  = (int*)p;              p += slotB;
    const size_t baseUsed = aggB + cntB + slotB;                // 64.2 MB

    const bool csr_ok  = ws_size >= baseUsed;
    const bool mfma_ok = ws_size >= baseUsed + wB;              // ~65.0 MB
    const bool hb_ok   = ws_size >= baseUsed + wB + hbB;        // ~90.6 MB

    hipMemsetAsync(agg, 0, aggB, stream);
    if (csr_ok) {
        hipMemsetAsync(cnt, 0, cntB, stream);
        k_fill<<<(EE + 255) / 256, 256, 0, stream>>>(x, ei, cnt, slot, agg);
        k_gather<<<(NN + 3) / 4, 256, 0, stream>>>(x, cnt, slot, agg);
    } else {
        k_scatter<<<EE / 4, 256, 0, stream>>>(x, ei, agg);
    }

    if (mfma_ok) {
        unsigned short* bWcT = (unsigned short*)p;  p += 131072 * 2;
        unsigned short* bW1T = (unsigned short*)p;  p += 131072 * 2;
        unsigned short* bW2T = (unsigned short*)p;  p += 131072 * 2;
        unsigned short* hb = hb_ok ? (unsigned short*)p : nullptr;
        k_cvtw<<<1536, 256, 0, stream>>>(Wn, Wr, W1, W2, bWcT, bW1T, bW2T);
        int g64 = (NN + 63) / 64;   // 782
        k2_mfma<<<g64, 256, 0, stream>>>(agg, x, bWcT, bg, g1, be1, out, hb);
        if (hb) k3_mfma<1><<<g64, 256, 0, stream>>>(out, hb, bW1T, bW2T, b1, b2, g2, be2);
        else    k3_mfma<0><<<g64, 256, 0, stream>>>(out, nullptr, bW1T, bW2T, b1, b2, g2, be2);
    } else {
        int nblk = (NN + 31) / 32;
        k_gnn_ln<<<nblk, 256, 0, stream>>>(x, agg, Wn, Wr, bg, g1, be1, out);
        k_ffn_ln<<<nblk, 256, 0, stream>>>(out, W1, b1, W2, b2, g2, be2);
    }
}